// Round 13
// baseline (1040.970 us; speedup 1.0000x reference)
//
#include <hip/hip_runtime.h>
#include <hip/hip_bf16.h>
#include <cstdint>

#define B_ 8
#define LABEL_NC 19
#define H_ 128
#define W_ 128
#define UC 640
#define EPS_ 1e-5f

typedef __attribute__((ext_vector_type(8))) short s8v;    // 8 bf16 (4 VGPR) MFMA frag
typedef __attribute__((ext_vector_type(4))) float f4v;    // MFMA acc
typedef __attribute__((ext_vector_type(4))) int i4v;      // 16B ld/st
typedef unsigned short ushort_t;

__device__ __forceinline__ ushort_t f2b(float f) {
    union { float f; uint32_t u; } a; a.f = f;
    uint32_t u = a.u;
    return (ushort_t)((u + 0x7FFFu + ((u >> 16) & 1u)) >> 16);  // RNE
}

__device__ __forceinline__ void gl2lds16(const ushort_t* g, ushort_t* l) {
    __builtin_amdgcn_global_load_lds(
        (const __attribute__((address_space(1))) unsigned int*)g,
        (__attribute__((address_space(3))) unsigned int*)l, 16, 0, 0);
}

// ---------------- fused aux kernel: buildU (1024 blocks) + stats (2048) + prep (2048) ----
__global__ void __launch_bounds__(256) k_aux(
    const float* __restrict__ x,
    const float* __restrict__ segmap, const float* __restrict__ style,
    const float* __restrict__ w_shared, const float* __restrict__ b_shared,
    const float* __restrict__ w_gamma, const float* __restrict__ w_beta,
    const float* __restrict__ w_sgamma, const float* __restrict__ w_sbeta,
    const float* __restrict__ b_gamma, const float* __restrict__ b_beta,
    const float* __restrict__ b_sgamma, const float* __restrict__ b_sbeta,
    const float* __restrict__ alpha_beta, const float* __restrict__ alpha_gamma,
    ushort_t* __restrict__ U, ushort_t* __restrict__ Wt,
    float* __restrict__ mean, float* __restrict__ rstd,
    float* __restrict__ bias_s, float* __restrict__ bias_o,
    float* __restrict__ zpage)
{
    __shared__ float seg[3][LABEL_NC][W_];
    int bid = blockIdx.x;

    if (bid < 1024) {
        // buildU
        int b = bid >> 7, h = bid & 127;
        const float* segb = segmap + (size_t)b * (LABEL_NC * H_ * W_);
        for (int idx = threadIdx.x; idx < 3 * LABEL_NC * W_; idx += 256) {
            int w = idx & 127;
            int l = (idx >> 7) % LABEL_NC;
            int rr = idx / (LABEL_NC * W_);
            int hh = h + rr - 1;
            seg[rr][l][w] = (hh >= 0 && hh < H_) ? segb[((size_t)l * H_ + hh) * W_ + w] : 0.f;
        }
        __syncthreads();

        int t = threadIdx.x;
        int w = t & 127;
        int grp = __builtin_amdgcn_readfirstlane(t >> 7);
        ushort_t* Urow = U + (((size_t)(b * H_ + h)) * W_ + w) * UC;

        union pack16 { ushort_t u[16]; i4v v[2]; };

        for (int cb = 0; cb < 4; ++cb) {
            int co0 = grp * 64 + cb * 16;
            float acc[16];
            #pragma unroll
            for (int i = 0; i < 16; ++i) acc[i] = b_shared[co0 + i];
            for (int l = 0; l < LABEL_NC; ++l) {
                #pragma unroll
                for (int kh = 0; kh < 3; ++kh) {
                    float sm = (w > 0)   ? seg[kh][l][w - 1] : 0.f;
                    float s0 = seg[kh][l][w];
                    float sp = (w < 127) ? seg[kh][l][w + 1] : 0.f;
                    const float* wp = w_shared + ((size_t)co0 * LABEL_NC + l) * 9 + kh * 3;
                    #pragma unroll
                    for (int i = 0; i < 16; ++i) {
                        const float* wpi = wp + i * (LABEL_NC * 9);
                        acc[i] += sm * wpi[0] + s0 * wpi[1] + sp * wpi[2];
                    }
                }
            }
            pack16 pk;
            #pragma unroll
            for (int i = 0; i < 16; ++i) pk.u[i] = f2b(acc[i] > 0.f ? acc[i] : 0.f);
            *(i4v*)(Urow + co0) = pk.v[0];
            *(i4v*)(Urow + co0 + 8) = pk.v[1];
        }

        float segr[LABEL_NC];
        #pragma unroll
        for (int l = 0; l < LABEL_NC; ++l) segr[l] = seg[1][l][w];
        const float* styb = style + (size_t)b * (LABEL_NC * 512);
        for (int sb = 0; sb < 16; ++sb) {
            int s0 = grp * 256 + sb * 16;
            float acc[16];
            #pragma unroll
            for (int i = 0; i < 16; ++i) acc[i] = 0.f;
            for (int l = 0; l < LABEL_NC; ++l) {
                const float* sp = styb + l * 512 + s0;
                float sl = segr[l];
                #pragma unroll
                for (int i = 0; i < 16; ++i) acc[i] += sl * sp[i];
            }
            pack16 pk;
            #pragma unroll
            for (int i = 0; i < 16; ++i) pk.u[i] = f2b(acc[i]);
            *(i4v*)(Urow + 128 + s0) = pk.v[0];
            *(i4v*)(Urow + 128 + s0 + 8) = pk.v[1];
        }
    } else if (bid < 3072) {
        // stats
        int bc = bid - 1024;
        const float4* p = (const float4*)(x + (size_t)bc * (H_ * W_));
        float s = 0.f, s2 = 0.f;
        for (int i = threadIdx.x; i < H_ * W_ / 4; i += 256) {
            float4 v = p[i];
            s += v.x + v.y + v.z + v.w;
            s2 += v.x * v.x + v.y * v.y + v.z * v.z + v.w * v.w;
        }
        #pragma unroll
        for (int o = 32; o > 0; o >>= 1) { s += __shfl_xor(s, o); s2 += __shfl_xor(s2, o); }
        __shared__ float red[8];
        int wave = threadIdx.x >> 6, lane = threadIdx.x & 63;
        if (lane == 0) { red[wave] = s; red[wave + 4] = s2; }
        __syncthreads();
        if (threadIdx.x == 0) {
            float ts = red[0] + red[1] + red[2] + red[3];
            float t2 = red[4] + red[5] + red[6] + red[7];
            float m = ts * (1.f / 16384.f);
            float v = t2 * (1.f / 16384.f) - m * m;
            mean[bc] = m;
            rstd[bc] = rsqrtf(v + EPS_);
        }
    } else {
        // prep
        float wb = 1.f / (1.f + __expf(-alpha_beta[0]));
        float wg = 1.f / (1.f + __expf(-alpha_gamma[0]));
        int gid = (bid - 3072) * 256 + threadIdx.x;
        if (gid < 256) bias_s[gid] = wg * b_sgamma[gid] + (1.f - wg) * b_gamma[gid];
        else if (gid < 512) bias_o[gid - 256] = wb * b_sbeta[gid - 256] + (1.f - wb) * b_beta[gid - 256];
        if (gid < 8192) zpage[gid] = 0.f;

        const int total = 9 * 512 * 640;
        for (int idx = gid; idx < total; idx += 2048 * 256) {
            int tap = idx / (512 * 640);
            int r = idx - tap * (512 * 640);
            int co = r / 640, ci = r - co * 640;
            int kh = tap / 3, kw = tap - kh * 3;
            float v;
            if (co < 256) {
                if (ci < 128) v = (1.f - wg) * w_gamma[((co * 128 + ci) * 3 + kh) * 3 + kw];
                else          v = wg * w_sgamma[((co * 512 + (ci - 128)) * 3 + kh) * 3 + kw];
            } else {
                int c2 = co - 256;
                if (ci < 128) v = (1.f - wb) * w_beta[((c2 * 128 + ci) * 3 + kh) * 3 + kw];
                else          v = wb * w_sbeta[((c2 * 512 + (ci - 128)) * 3 + kh) * 3 + kw];
            }
            Wt[idx] = f2b(v);
        }
    }
}

// ---------------- kernel 3: implicit-GEMM conv, 2-blocks/CU stagger version ----------------
// 256 threads (4 waves, 2wm x 2wn). Tile: M = 128 px (one image row h), N = 128 GEMM cols
// (64 scale + 64 offset of 64 output channels; chq in [0,4) picks the channel quarter).
// Grid 4096. LDS = A dbuf 2x24KB (3 halo rows x 128 px x 32 ci) + B 3x8KB = 72KB ->
// 2 blocks/CU with INDEPENDENT barrier domains -> one block's ds_read phase overlaps the
// other's MFMA phase (m114 mechanism). acc[4][4]=64 VGPR.
// Pipeline: B(g) staged at g-2, 3 slots; A' staged at tap 7; counted vmcnt: steady 2,
// tap8 = 8 (B(0')2 + A'6 newer), final body 0.
// LDS slot swizzle: phys_slot = data_slot ^ ((row>>1)&3) (conflict-free, R6-verified).
#define BK 32

__global__ void __launch_bounds__(256, 2) k_conv(
    const ushort_t* __restrict__ U, const ushort_t* __restrict__ Wt,
    const ushort_t* __restrict__ zp,
    const float* __restrict__ x, const float* __restrict__ mean, const float* __restrict__ rstd,
    const float* __restrict__ bias_s, const float* __restrict__ bias_o,
    float* __restrict__ out)
{
    // bijective XCD swizzle (4096 = 8 x 512); same-XCD neighbors share A (chq) and Wt (h)
    int orig = blockIdx.x;
    int wg = (orig & 7) * 512 + (orig >> 3);
    int mrow = wg >> 2;            // b*128 + h
    int chq = wg & 3;              // channel quarter (64 channels)
    int b = mrow >> 7;
    int h = mrow & 127;

    extern __shared__ ushort_t smem[];
    // smem + ab*12288       : sA[2] (3 rows x 128 px x 32 ci = 24KB each)
    // smem + 24576 + bi*4096: sB[3] (128 gemm-cols x 32 ci = 8KB each)

    int t = threadIdx.x;
    int wv = t >> 6, ln = t & 63;
    int wm = wv >> 1, wn = wv & 1;
    int sd = ln >> 4;              // 16B k-slot

    const ushort_t* Ub = U + (size_t)b * (H_ * W_ * UC);

    f4v acc[4][4] = {};   // [mi][ni]; ni 0,1 = scale, 2,3 = offset (same channels)

    auto stage_A = [&](int ci0, int ab) {      // 6 loads/thread -> 24KB (3 halo rows)
        ushort_t* sAb = smem + ab * 12288;
        #pragma unroll
        for (int i = 0; i < 6; ++i) {
            int issue = wv * 6 + i;            // 24 issues of 1KB
            int rr = issue >> 3;               // halo row 0..2 (uniform per issue)
            int hh = h - 1 + rr;
            int w = (issue & 7) * 16 + (ln >> 2);
            int sl = (ln & 3) ^ ((w >> 1) & 3);
            const ushort_t* src = (hh >= 0 && hh < H_)
                ? Ub + ((size_t)hh * W_ + w) * UC + ci0 + (sl << 3)
                : zp + (size_t)ln * 8;
            gl2lds16(src, sAb + (size_t)issue * 512);
        }
    };
    auto stage_B = [&](int tapX, int ci0X, int bi) {   // 2 loads/thread -> 8KB
        ushort_t* base = smem + 24576 + bi * 4096;
        #pragma unroll
        for (int j = 0; j < 2; ++j) {
            int issue = wv * 2 + j;            // 8 issues of 1KB
            int c = issue * 16 + (ln >> 2);    // gemm col 0..127
            int sl = (ln & 3) ^ ((c >> 1) & 3);
            int co = ((c >> 6) << 8) + chq * 64 + (c & 63);   // scale or offset row
            const ushort_t* src = Wt + ((size_t)tapX * 512 + co) * UC + ci0X + (sl << 3);
            gl2lds16(src, base + (size_t)issue * 512);
        }
    };

    // ---- prologue ----
    stage_A(0, 0);
    stage_B(0, 0, 0);
    stage_B(1, 0, 1);

    for (int ch = 0; ch < 20; ++ch) {
        int ci0 = ch * BK;
        ushort_t* sAb = smem + (ch & 1) * 12288;
        bool lastch = (ch == 19);
        #pragma unroll
        for (int tap = 0; tap < 9; ++tap) {
            const int dhp1 = tap / 3;
            const int dw = tap - dhp1 * 3 - 1;
            const int bi = tap % 3;
            const int bi2 = (tap + 2) % 3;

            if (tap == 8) {
                if (lastch) { asm volatile("s_waitcnt vmcnt(0)" ::: "memory"); }
                else        { asm volatile("s_waitcnt vmcnt(8)" ::: "memory"); }
            } else          { asm volatile("s_waitcnt vmcnt(2)" ::: "memory"); }
            __builtin_amdgcn_s_barrier();

            if (tap < 7)        stage_B(tap + 2, ci0, bi2);
            else if (!lastch) {
                if (tap == 7) { stage_B(0, ci0 + BK, bi2); stage_A(ci0 + BK, (ch + 1) & 1); }
                else          stage_B(1, ci0 + BK, bi2);
            }

            // ---- A-frags from sA row dhp1 (dw shift) ----
            s8v af[4];
            #pragma unroll
            for (int mi = 0; mi < 4; ++mi) {
                int p = wm * 64 + mi * 16 + (ln & 15);
                int q = p + dw;
                int qc = q < 0 ? 0 : (q > 127 ? 127 : q);
                s8v v = *(const s8v*)&sAb[(size_t)(((dhp1 * 128 + qc) << 2) + (sd ^ ((qc >> 1) & 3))) * 8];
                if (dw != 0 && (q < 0 || q > 127)) { s8v z = {}; v = z; }
                af[mi] = v;
            }
            // ---- B-frags from sB[bi] ----
            ushort_t* sBb = smem + 24576 + bi * 4096;
            s8v bf[4];
            #pragma unroll
            for (int ni = 0; ni < 4; ++ni) {
                int c = ((ni >> 1) << 6) + wn * 32 + (ni & 1) * 16 + (ln & 15);
                bf[ni] = *(const s8v*)&sBb[(size_t)((c << 2) + (sd ^ ((c >> 1) & 3))) * 8];
            }

            __builtin_amdgcn_s_setprio(1);
            #pragma unroll
            for (int mi = 0; mi < 4; ++mi)
                #pragma unroll
                for (int ni = 0; ni < 4; ++ni)
                    acc[mi][ni] = __builtin_amdgcn_mfma_f32_16x16x32_bf16(
                        af[mi], bf[ni], acc[mi][ni], 0, 0, 0);
            __builtin_amdgcn_s_setprio(0);
        }
    }

    // ---- fused epilogue: out = (x-mu)*rstd*(scale+bs+1) + (offset+bo) ----
    int bc_base = b * 256;
    #pragma unroll
    for (int ni = 0; ni < 2; ++ni) {
        int chn = chq * 64 + wn * 32 + ni * 16 + (ln & 15);
        float bs = bias_s[chn] + 1.f;
        float bo = bias_o[chn];
        float mu = mean[bc_base + chn];
        float rs = rstd[bc_base + chn];
        #pragma unroll
        for (int mi = 0; mi < 4; ++mi) {
            #pragma unroll
            for (int r = 0; r < 4; ++r) {
                int p = wm * 64 + mi * 16 + ((ln >> 4) << 2) + r;
                size_t xi = (((size_t)(bc_base + chn)) * H_ + h) * W_ + p;
                float xn = (x[xi] - mu) * rs;
                out[xi] = xn * (acc[mi][ni][r] + bs) + (acc[mi][ni + 2][r] + bo);
            }
        }
    }
}

// ---------------- launcher ----------------
extern "C" void kernel_launch(void* const* d_in, const int* in_sizes, int n_in,
                              void* d_out, int out_size, void* d_ws, size_t ws_size,
                              hipStream_t stream)
{
    const float* x        = (const float*)d_in[0];
    const float* segmap   = (const float*)d_in[1];
    const float* style    = (const float*)d_in[2];
    const float* w_shared = (const float*)d_in[3];
    const float* b_shared = (const float*)d_in[4];
    const float* w_gamma  = (const float*)d_in[5];
    const float* b_gamma  = (const float*)d_in[6];
    const float* w_beta   = (const float*)d_in[7];
    const float* b_beta   = (const float*)d_in[8];
    const float* w_sgamma = (const float*)d_in[9];
    const float* b_sgamma = (const float*)d_in[10];
    const float* w_sbeta  = (const float*)d_in[11];
    const float* b_sbeta  = (const float*)d_in[12];
    const float* alpha_beta  = (const float*)d_in[13];
    const float* alpha_gamma = (const float*)d_in[14];
    float* out = (float*)d_out;

    char* ws = (char*)d_ws;
    float*    ws_mean  = (float*)(ws + 0);            // 2048 f32
    float*    ws_rstd  = (float*)(ws + 8192);         // 2048 f32
    float*    ws_bs    = (float*)(ws + 16384);        // 256 f32
    float*    ws_bo    = (float*)(ws + 18432);        // 256 f32
    ushort_t* ws_Wt    = (ushort_t*)(ws + 20480);     // 9*512*640 bf16 = 5.9 MB
    ushort_t* ws_zp    = (ushort_t*)(ws + 6 * 1024 * 1024 - 65536);  // 32KB zero page
    ushort_t* ws_U     = (ushort_t*)(ws + 6 * 1024 * 1024);  // 8*128*128*640 bf16 = 167.8 MB

    (void)hipFuncSetAttribute((const void*)k_conv,
                              hipFuncAttributeMaxDynamicSharedMemorySize, 73728);

    k_aux<<<dim3(5120), dim3(256), 0, stream>>>(x, segmap, style, w_shared, b_shared,
                                                w_gamma, w_beta, w_sgamma, w_sbeta,
                                                b_gamma, b_beta, b_sgamma, b_sbeta,
                                                alpha_beta, alpha_gamma,
                                                ws_U, ws_Wt, ws_mean, ws_rstd,
                                                ws_bs, ws_bo, (float*)ws_zp);
    k_conv<<<dim3(4096), dim3(256), 73728, stream>>>(ws_U, ws_Wt, ws_zp, x, ws_mean, ws_rstd,
                                                     ws_bs, ws_bo, out);
}

// Round 14
// 1006.540 us; speedup vs baseline: 1.0342x; 1.0342x over previous
//
#include <hip/hip_runtime.h>
#include <hip/hip_bf16.h>
#include <cstdint>

#define B_ 8
#define LABEL_NC 19
#define H_ 128
#define W_ 128
#define UC 640
#define EPS_ 1e-5f

typedef __attribute__((ext_vector_type(8))) short s8v;     // 8 bf16 (4 VGPR) MFMA frag
typedef __attribute__((ext_vector_type(16))) float f16v;   // 32x32 MFMA acc
typedef __attribute__((ext_vector_type(4))) int i4v;       // 16B ld/st
typedef unsigned short ushort_t;

__device__ __forceinline__ ushort_t f2b(float f) {
    union { float f; uint32_t u; } a; a.f = f;
    uint32_t u = a.u;
    return (ushort_t)((u + 0x7FFFu + ((u >> 16) & 1u)) >> 16);  // RNE
}

__device__ __forceinline__ void gl2lds16(const ushort_t* g, ushort_t* l) {
    __builtin_amdgcn_global_load_lds(
        (const __attribute__((address_space(1))) unsigned int*)g,
        (__attribute__((address_space(3))) unsigned int*)l, 16, 0, 0);
}

// ---------------- fused aux kernel: buildU (1024 blocks) + stats (2048) + prep (2048) ----
__global__ void __launch_bounds__(256) k_aux(
    const float* __restrict__ x,
    const float* __restrict__ segmap, const float* __restrict__ style,
    const float* __restrict__ w_shared, const float* __restrict__ b_shared,
    const float* __restrict__ w_gamma, const float* __restrict__ w_beta,
    const float* __restrict__ w_sgamma, const float* __restrict__ w_sbeta,
    const float* __restrict__ b_gamma, const float* __restrict__ b_beta,
    const float* __restrict__ b_sgamma, const float* __restrict__ b_sbeta,
    const float* __restrict__ alpha_beta, const float* __restrict__ alpha_gamma,
    ushort_t* __restrict__ U, ushort_t* __restrict__ Wt,
    float* __restrict__ mean, float* __restrict__ rstd,
    float* __restrict__ bias_s, float* __restrict__ bias_o,
    float* __restrict__ zpage)
{
    __shared__ float seg[3][LABEL_NC][W_];
    int bid = blockIdx.x;

    if (bid < 1024) {
        // buildU
        int b = bid >> 7, h = bid & 127;
        const float* segb = segmap + (size_t)b * (LABEL_NC * H_ * W_);
        for (int idx = threadIdx.x; idx < 3 * LABEL_NC * W_; idx += 256) {
            int w = idx & 127;
            int l = (idx >> 7) % LABEL_NC;
            int rr = idx / (LABEL_NC * W_);
            int hh = h + rr - 1;
            seg[rr][l][w] = (hh >= 0 && hh < H_) ? segb[((size_t)l * H_ + hh) * W_ + w] : 0.f;
        }
        __syncthreads();

        int t = threadIdx.x;
        int w = t & 127;
        int grp = __builtin_amdgcn_readfirstlane(t >> 7);
        ushort_t* Urow = U + (((size_t)(b * H_ + h)) * W_ + w) * UC;

        union pack16 { ushort_t u[16]; i4v v[2]; };

        for (int cb = 0; cb < 4; ++cb) {
            int co0 = grp * 64 + cb * 16;
            float acc[16];
            #pragma unroll
            for (int i = 0; i < 16; ++i) acc[i] = b_shared[co0 + i];
            for (int l = 0; l < LABEL_NC; ++l) {
                #pragma unroll
                for (int kh = 0; kh < 3; ++kh) {
                    float sm = (w > 0)   ? seg[kh][l][w - 1] : 0.f;
                    float s0 = seg[kh][l][w];
                    float sp = (w < 127) ? seg[kh][l][w + 1] : 0.f;
                    const float* wp = w_shared + ((size_t)co0 * LABEL_NC + l) * 9 + kh * 3;
                    #pragma unroll
                    for (int i = 0; i < 16; ++i) {
                        const float* wpi = wp + i * (LABEL_NC * 9);
                        acc[i] += sm * wpi[0] + s0 * wpi[1] + sp * wpi[2];
                    }
                }
            }
            pack16 pk;
            #pragma unroll
            for (int i = 0; i < 16; ++i) pk.u[i] = f2b(acc[i] > 0.f ? acc[i] : 0.f);
            *(i4v*)(Urow + co0) = pk.v[0];
            *(i4v*)(Urow + co0 + 8) = pk.v[1];
        }

        float segr[LABEL_NC];
        #pragma unroll
        for (int l = 0; l < LABEL_NC; ++l) segr[l] = seg[1][l][w];
        const float* styb = style + (size_t)b * (LABEL_NC * 512);
        for (int sb = 0; sb < 16; ++sb) {
            int s0 = grp * 256 + sb * 16;
            float acc[16];
            #pragma unroll
            for (int i = 0; i < 16; ++i) acc[i] = 0.f;
            for (int l = 0; l < LABEL_NC; ++l) {
                const float* sp = styb + l * 512 + s0;
                float sl = segr[l];
                #pragma unroll
                for (int i = 0; i < 16; ++i) acc[i] += sl * sp[i];
            }
            pack16 pk;
            #pragma unroll
            for (int i = 0; i < 16; ++i) pk.u[i] = f2b(acc[i]);
            *(i4v*)(Urow + 128 + s0) = pk.v[0];
            *(i4v*)(Urow + 128 + s0 + 8) = pk.v[1];
        }
    } else if (bid < 3072) {
        // stats
        int bc = bid - 1024;
        const float4* p = (const float4*)(x + (size_t)bc * (H_ * W_));
        float s = 0.f, s2 = 0.f;
        for (int i = threadIdx.x; i < H_ * W_ / 4; i += 256) {
            float4 v = p[i];
            s += v.x + v.y + v.z + v.w;
            s2 += v.x * v.x + v.y * v.y + v.z * v.z + v.w * v.w;
        }
        #pragma unroll
        for (int o = 32; o > 0; o >>= 1) { s += __shfl_xor(s, o); s2 += __shfl_xor(s2, o); }
        __shared__ float red[8];
        int wave = threadIdx.x >> 6, lane = threadIdx.x & 63;
        if (lane == 0) { red[wave] = s; red[wave + 4] = s2; }
        __syncthreads();
        if (threadIdx.x == 0) {
            float ts = red[0] + red[1] + red[2] + red[3];
            float t2 = red[4] + red[5] + red[6] + red[7];
            float m = ts * (1.f / 16384.f);
            float v = t2 * (1.f / 16384.f) - m * m;
            mean[bc] = m;
            rstd[bc] = rsqrtf(v + EPS_);
        }
    } else {
        // prep
        float wb = 1.f / (1.f + __expf(-alpha_beta[0]));
        float wg = 1.f / (1.f + __expf(-alpha_gamma[0]));
        int gid = (bid - 3072) * 256 + threadIdx.x;
        if (gid < 256) bias_s[gid] = wg * b_sgamma[gid] + (1.f - wg) * b_gamma[gid];
        else if (gid < 512) bias_o[gid - 256] = wb * b_sbeta[gid - 256] + (1.f - wb) * b_beta[gid - 256];
        if (gid < 8192) zpage[gid] = 0.f;

        const int total = 9 * 512 * 640;
        for (int idx = gid; idx < total; idx += 2048 * 256) {
            int tap = idx / (512 * 640);
            int r = idx - tap * (512 * 640);
            int co = r / 640, ci = r - co * 640;
            int kh = tap / 3, kw = tap - kh * 3;
            float v;
            if (co < 256) {
                if (ci < 128) v = (1.f - wg) * w_gamma[((co * 128 + ci) * 3 + kh) * 3 + kw];
                else          v = wg * w_sgamma[((co * 512 + (ci - 128)) * 3 + kh) * 3 + kw];
            } else {
                int c2 = co - 256;
                if (ci < 128) v = (1.f - wb) * w_beta[((c2 * 128 + ci) * 3 + kh) * 3 + kw];
                else          v = wb * w_sbeta[((c2 * 512 + (ci - 128)) * 3 + kh) * 3 + kw];
            }
            Wt[idx] = f2b(v);
        }
    }
}

// ---------------- kernel 3: implicit-GEMM conv, 32x32x16 MFMA + hoisted addressing -------
// 512 threads (8 waves, 4wm x 2wn). M = 256 px (2 rows), N = 256 gemm cols (scale/offset
// interleaved in 64-col blocks). Wave tile 64x128 = 2x4 tiles of 32x32; K=32/body = 2
// k-steps of 16. Pipeline identical to R12 (B 3-slot staged 2-ahead, A dbuf at tap 7,
// counted vmcnt 2/6/0, one barrier per body). LDS 112KB.
// All frag LDS indices and staging global pointers PRECOMPUTED per-lane before the loop;
// per tap only compile-time/uniform offsets are added -> per-body VALU ~= 2 edge cndmasks.
// 32x32x16 frag mapping: A row=ln&31 (pixel), k-slot=ln>>5; B col=ln&31 (channel);
// D col=ln&31, row=(r&3)+8*(r>>2)+4*(ln>>5) [m74/m101-verified] -> float4 epilogue.
// LDS slot swizzle: phys_slot = data_slot ^ ((row>>1)&3) (8 distinct 16B offsets/8 lanes).
#define BK 32

__global__ void __launch_bounds__(512, 1) k_conv(
    const ushort_t* __restrict__ U, const ushort_t* __restrict__ Wt,
    const ushort_t* __restrict__ zp,
    const float* __restrict__ x, const float* __restrict__ mean, const float* __restrict__ rstd,
    const float* __restrict__ bias_s, const float* __restrict__ bias_o,
    float* __restrict__ out)
{
    // bijective XCD-chunk swizzle (nwg=1024, 128 per XCD)
    int orig = blockIdx.x;
    int wg = (orig & 7) * 128 + (orig >> 3);
    int mtile = wg >> 1;
    int cohalf = wg & 1;
    int b = mtile >> 6;
    int h0 = (mtile & 63) << 1;

    extern __shared__ ushort_t smem[];
    // smem + ab*16384        : sA[2]  (each [4 halo rows x 128 px][4 slots x 8ci] = 32KB)
    // smem + 32768 + bi*8192 : sB[3]  (each [256 gemm cols][4 slots x 8ci] = 16KB)

    int t = threadIdx.x;
    int wv = t >> 6, ln = t & 63;
    int wm = wv >> 1, wn = wv & 1;

    const ushort_t* Ub = U + (size_t)b * (H_ * W_ * UC);

    f16v acc[2][4] = {};   // [mi][ni]; ni 0,1 = scale, 2,3 = offset (paired channels)

    // ---- precomputed per-lane frag LDS indices (in s8v units: byte = idx*16) ----
    int aidx[3][2][2];   // [dwi][mi][ks]
    #pragma unroll
    for (int dwi = 0; dwi < 3; ++dwi)
        #pragma unroll
        for (int mi = 0; mi < 2; ++mi) {
            int p = wm * 64 + mi * 32 + (ln & 31);
            int px = p & 127;
            int rb = p >> 7;
            int q = px + dwi - 1;
            int qc = q < 0 ? 0 : (q > 127 ? 127 : q);
            #pragma unroll
            for (int ks = 0; ks < 2; ++ks) {
                int slot = (ks * 2 + (ln >> 5)) ^ ((qc >> 1) & 3);
                aidx[dwi][mi][ks] = ((rb * 128 + qc) << 2) + slot;
            }
        }
    int bidx[4][2];      // [ni][ks]
    #pragma unroll
    for (int ni = 0; ni < 4; ++ni) {
        int c = wn * 128 + ni * 32 + (ln & 31);
        #pragma unroll
        for (int ks = 0; ks < 2; ++ks)
            bidx[ni][ks] = (c << 2) + ((ks * 2 + (ln >> 5)) ^ ((c >> 1) & 3));
    }
    // edge-halo zero guards (pixel 0 / pixel 127; must include (wm&1) -- R9 lesson)
    bool zlo = ((wm & 1) == 0) && ((ln & 31) == 0);    // dw=-1, mi=0
    bool zhi = ((wm & 1) == 1) && ((ln & 31) == 31);   // dw=+1, mi=1

    // ---- precomputed staging pointers ----
    const ushort_t* pA[4];
    #pragma unroll
    for (int i = 0; i < 4; ++i) {
        int issue = wv * 4 + i;
        int hh = h0 - 1 + (issue >> 3);
        int w = issue * 16 + (ln >> 2);
        int sl = (ln & 3) ^ ((w >> 1) & 3);
        pA[i] = (hh >= 0 && hh < H_)
            ? Ub + ((size_t)hh * W_ + (w & 127)) * UC + (sl << 3)
            : zp + (size_t)ln * 8;
    }
    const ushort_t* pB[2];
    #pragma unroll
    for (int j = 0; j < 2; ++j) {
        int issue = wv * 2 + j;
        int c = issue * 16 + (ln >> 2);
        int sl = (ln & 3) ^ ((c >> 1) & 3);
        int gq = (c >> 6) & 1;
        int cbase = ((c >> 7) << 6) + (c & 63);
        int co = gq * 256 + cohalf * 128 + cbase;
        pB[j] = Wt + (size_t)co * UC + (sl << 3);
    }

    auto stage_A = [&](int ci0, int ab) {
        ushort_t* sAb = smem + ab * 16384;
        #pragma unroll
        for (int i = 0; i < 4; ++i)
            gl2lds16(pA[i] + ci0, sAb + (size_t)(wv * 4 + i) * 512);
    };
    auto stage_B = [&](int tapX, int ci0X, int bi) {
        ushort_t* base = smem + 32768 + bi * 8192;
        size_t off = (size_t)tapX * (512 * UC) + ci0X;
        #pragma unroll
        for (int j = 0; j < 2; ++j)
            gl2lds16(pB[j] + off, base + (size_t)(wv * 2 + j) * 512);
    };

    // ---- prologue: A(ch0), B(g=0), B(g=1) ----
    stage_A(0, 0);
    stage_B(0, 0, 0);
    stage_B(1, 0, 1);

    for (int ch = 0; ch < 20; ++ch) {
        int ci0 = ch * BK;
        ushort_t* sAb = smem + (ch & 1) * 16384;
        bool lastch = (ch == 19);
        #pragma unroll
        for (int tap = 0; tap < 9; ++tap) {
            const int dhp1 = tap / 3;            // compile-time after unroll
            const int dwi = tap % 3;             // dw = dwi-1
            const int bi = tap % 3;
            const int bi2 = (tap + 2) % 3;

            if (tap == 8) {
                if (lastch) { asm volatile("s_waitcnt vmcnt(0)" ::: "memory"); }
                else        { asm volatile("s_waitcnt vmcnt(6)" ::: "memory"); }
            } else          { asm volatile("s_waitcnt vmcnt(2)" ::: "memory"); }
            __builtin_amdgcn_s_barrier();

            if (tap < 7)        stage_B(tap + 2, ci0, bi2);
            else if (!lastch) {
                if (tap == 7) { stage_B(0, ci0 + BK, bi2); stage_A(ci0 + BK, (ch + 1) & 1); }
                else          stage_B(1, ci0 + BK, bi2);
            }

            ushort_t* sBb = smem + 32768 + bi * 8192;
            #pragma unroll
            for (int ks = 0; ks < 2; ++ks) {
                s8v af[2], bf[4];
                #pragma unroll
                for (int mi = 0; mi < 2; ++mi)
                    af[mi] = *(const s8v*)&sAb[(size_t)(aidx[dwi][mi][ks] + dhp1 * 512) * 8];
                if (dwi == 0) { if (zlo) { s8v z = {}; af[0] = z; } }
                if (dwi == 2) { if (zhi) { s8v z = {}; af[1] = z; } }
                #pragma unroll
                for (int ni = 0; ni < 4; ++ni)
                    bf[ni] = *(const s8v*)&sBb[(size_t)bidx[ni][ks] * 8];

                __builtin_amdgcn_s_setprio(1);
                #pragma unroll
                for (int mi = 0; mi < 2; ++mi)
                    #pragma unroll
                    for (int ni = 0; ni < 4; ++ni)
                        acc[mi][ni] = __builtin_amdgcn_mfma_f32_32x32x16_bf16(
                            af[mi], bf[ni], acc[mi][ni], 0, 0, 0);
                __builtin_amdgcn_s_setprio(0);
            }
        }
    }

    // ---- fused epilogue (float4): out = (x-mu)*rstd*(scale+bs+1) + (offset+bo) ----
    int bc_base = b * 256;
    #pragma unroll
    for (int ni = 0; ni < 2; ++ni) {
        int chn = cohalf * 128 + wn * 64 + ni * 32 + (ln & 31);
        float bs = bias_s[chn] + 1.f;
        float bo = bias_o[chn];
        float mu = mean[bc_base + chn];
        float rs = rstd[bc_base + chn];
        #pragma unroll
        for (int mi = 0; mi < 2; ++mi) {
            #pragma unroll
            for (int rg = 0; rg < 4; ++rg) {
                int p4 = wm * 64 + mi * 32 + rg * 8 + ((ln >> 5) << 2);
                int hh = h0 + (p4 >> 7);
                int ww = p4 & 127;
                size_t xi = (((size_t)(bc_base + chn)) * H_ + hh) * W_ + ww;
                float4 xv = *(const float4*)&x[xi];
                float4 ov;
                ov.x = (xv.x - mu) * rs * (acc[mi][ni][rg * 4 + 0] + bs) + (acc[mi][ni + 2][rg * 4 + 0] + bo);
                ov.y = (xv.y - mu) * rs * (acc[mi][ni][rg * 4 + 1] + bs) + (acc[mi][ni + 2][rg * 4 + 1] + bo);
                ov.z = (xv.z - mu) * rs * (acc[mi][ni][rg * 4 + 2] + bs) + (acc[mi][ni + 2][rg * 4 + 2] + bo);
                ov.w = (xv.w - mu) * rs * (acc[mi][ni][rg * 4 + 3] + bs) + (acc[mi][ni + 2][rg * 4 + 3] + bo);
                *(float4*)&out[xi] = ov;
            }
        }
    }
}

// ---------------- launcher ----------------
extern "C" void kernel_launch(void* const* d_in, const int* in_sizes, int n_in,
                              void* d_out, int out_size, void* d_ws, size_t ws_size,
                              hipStream_t stream)
{
    const float* x        = (const float*)d_in[0];
    const float* segmap   = (const float*)d_in[1];
    const float* style    = (const float*)d_in[2];
    const float* w_shared = (const float*)d_in[3];
    const float* b_shared = (const float*)d_in[4];
    const float* w_gamma  = (const float*)d_in[5];
    const float* b_gamma  = (const float*)d_in[6];
    const float* w_beta   = (const float*)d_in[7];
    const float* b_beta   = (const float*)d_in[8];
    const float* w_sgamma = (const float*)d_in[9];
    const float* b_sgamma = (const float*)d_in[10];
    const float* w_sbeta  = (const float*)d_in[11];
    const float* b_sbeta  = (const float*)d_in[12];
    const float* alpha_beta  = (const float*)d_in[13];
    const float* alpha_gamma = (const float*)d_in[14];
    float* out = (float*)d_out;

    char* ws = (char*)d_ws;
    float*    ws_mean  = (float*)(ws + 0);            // 2048 f32
    float*    ws_rstd  = (float*)(ws + 8192);         // 2048 f32
    float*    ws_bs    = (float*)(ws + 16384);        // 256 f32
    float*    ws_bo    = (float*)(ws + 18432);        // 256 f32
    ushort_t* ws_Wt    = (ushort_t*)(ws + 20480);     // 9*512*640 bf16 = 5.9 MB
    ushort_t* ws_zp    = (ushort_t*)(ws + 6 * 1024 * 1024 - 65536);  // 32KB zero page
    ushort_t* ws_U     = (ushort_t*)(ws + 6 * 1024 * 1024);  // 8*128*128*640 bf16 = 167.8 MB

    (void)hipFuncSetAttribute((const void*)k_conv,
                              hipFuncAttributeMaxDynamicSharedMemorySize, 114688);

    k_aux<<<dim3(5120), dim3(256), 0, stream>>>(x, segmap, style, w_shared, b_shared,
                                                w_gamma, w_beta, w_sgamma, w_sbeta,
                                                b_gamma, b_beta, b_sgamma, b_sbeta,
                                                alpha_beta, alpha_gamma,
                                                ws_U, ws_Wt, ws_mean, ws_rstd,
                                                ws_bs, ws_bo, (float*)ws_zp);
    k_conv<<<dim3(1024), dim3(512), 114688, stream>>>(ws_U, ws_Wt, ws_zp, x, ws_mean, ws_rstd,
                                                      ws_bs, ws_bo, out);
}

// Round 18
// 924.588 us; speedup vs baseline: 1.1259x; 1.0886x over previous
//
#include <hip/hip_runtime.h>
#include <hip/hip_bf16.h>
#include <cstdint>

#define B_ 8
#define LABEL_NC 19
#define H_ 128
#define W_ 128
#define UC 640
#define EPS_ 1e-5f

typedef __attribute__((ext_vector_type(8))) short s8v;    // 8 bf16 (4 VGPR) MFMA frag
typedef __attribute__((ext_vector_type(4))) float f4v;    // MFMA acc
typedef __attribute__((ext_vector_type(4))) int i4v;      // 16B ld/st
typedef unsigned short ushort_t;

__device__ __forceinline__ ushort_t f2b(float f) {
    union { float f; uint32_t u; } a; a.f = f;
    uint32_t u = a.u;
    return (ushort_t)((u + 0x7FFFu + ((u >> 16) & 1u)) >> 16);  // RNE
}

__device__ __forceinline__ void gl2lds16(const ushort_t* g, ushort_t* l) {
    __builtin_amdgcn_global_load_lds(
        (const __attribute__((address_space(1))) unsigned int*)g,
        (__attribute__((address_space(3))) unsigned int*)l, 16, 0, 0);
}

// ---------------- fused aux kernel: buildU (1024 blocks) + stats (2048) + prep (2048) ----
__global__ void __launch_bounds__(256) k_aux(
    const float* __restrict__ x,
    const float* __restrict__ segmap, const float* __restrict__ style,
    const float* __restrict__ w_shared, const float* __restrict__ b_shared,
    const float* __restrict__ w_gamma, const float* __restrict__ w_beta,
    const float* __restrict__ w_sgamma, const float* __restrict__ w_sbeta,
    const float* __restrict__ b_gamma, const float* __restrict__ b_beta,
    const float* __restrict__ b_sgamma, const float* __restrict__ b_sbeta,
    const float* __restrict__ alpha_beta, const float* __restrict__ alpha_gamma,
    ushort_t* __restrict__ U, ushort_t* __restrict__ Wt,
    float* __restrict__ mean, float* __restrict__ rstd,
    float* __restrict__ bias_s, float* __restrict__ bias_o,
    float* __restrict__ zpage)
{
    __shared__ float seg[3][LABEL_NC][W_];
    int bid = blockIdx.x;

    if (bid < 1024) {
        // buildU
        int b = bid >> 7, h = bid & 127;
        const float* segb = segmap + (size_t)b * (LABEL_NC * H_ * W_);
        for (int idx = threadIdx.x; idx < 3 * LABEL_NC * W_; idx += 256) {
            int w = idx & 127;
            int l = (idx >> 7) % LABEL_NC;
            int rr = idx / (LABEL_NC * W_);
            int hh = h + rr - 1;
            seg[rr][l][w] = (hh >= 0 && hh < H_) ? segb[((size_t)l * H_ + hh) * W_ + w] : 0.f;
        }
        __syncthreads();

        int t = threadIdx.x;
        int w = t & 127;
        int grp = __builtin_amdgcn_readfirstlane(t >> 7);
        ushort_t* Urow = U + (((size_t)(b * H_ + h)) * W_ + w) * UC;

        union pack16 { ushort_t u[16]; i4v v[2]; };

        for (int cb = 0; cb < 4; ++cb) {
            int co0 = grp * 64 + cb * 16;
            float acc[16];
            #pragma unroll
            for (int i = 0; i < 16; ++i) acc[i] = b_shared[co0 + i];
            for (int l = 0; l < LABEL_NC; ++l) {
                #pragma unroll
                for (int kh = 0; kh < 3; ++kh) {
                    float sm = (w > 0)   ? seg[kh][l][w - 1] : 0.f;
                    float s0 = seg[kh][l][w];
                    float sp = (w < 127) ? seg[kh][l][w + 1] : 0.f;
                    const float* wp = w_shared + ((size_t)co0 * LABEL_NC + l) * 9 + kh * 3;
                    #pragma unroll
                    for (int i = 0; i < 16; ++i) {
                        const float* wpi = wp + i * (LABEL_NC * 9);
                        acc[i] += sm * wpi[0] + s0 * wpi[1] + sp * wpi[2];
                    }
                }
            }
            pack16 pk;
            #pragma unroll
            for (int i = 0; i < 16; ++i) pk.u[i] = f2b(acc[i] > 0.f ? acc[i] : 0.f);
            *(i4v*)(Urow + co0) = pk.v[0];
            *(i4v*)(Urow + co0 + 8) = pk.v[1];
        }

        float segr[LABEL_NC];
        #pragma unroll
        for (int l = 0; l < LABEL_NC; ++l) segr[l] = seg[1][l][w];
        const float* styb = style + (size_t)b * (LABEL_NC * 512);
        for (int sb = 0; sb < 16; ++sb) {
            int s0 = grp * 256 + sb * 16;
            float acc[16];
            #pragma unroll
            for (int i = 0; i < 16; ++i) acc[i] = 0.f;
            for (int l = 0; l < LABEL_NC; ++l) {
                const float* sp = styb + l * 512 + s0;
                float sl = segr[l];
                #pragma unroll
                for (int i = 0; i < 16; ++i) acc[i] += sl * sp[i];
            }
            pack16 pk;
            #pragma unroll
            for (int i = 0; i < 16; ++i) pk.u[i] = f2b(acc[i]);
            *(i4v*)(Urow + 128 + s0) = pk.v[0];
            *(i4v*)(Urow + 128 + s0 + 8) = pk.v[1];
        }
    } else if (bid < 3072) {
        // stats
        int bc = bid - 1024;
        const float4* p = (const float4*)(x + (size_t)bc * (H_ * W_));
        float s = 0.f, s2 = 0.f;
        for (int i = threadIdx.x; i < H_ * W_ / 4; i += 256) {
            float4 v = p[i];
            s += v.x + v.y + v.z + v.w;
            s2 += v.x * v.x + v.y * v.y + v.z * v.z + v.w * v.w;
        }
        #pragma unroll
        for (int o = 32; o > 0; o >>= 1) { s += __shfl_xor(s, o); s2 += __shfl_xor(s2, o); }
        __shared__ float red[8];
        int wave = threadIdx.x >> 6, lane = threadIdx.x & 63;
        if (lane == 0) { red[wave] = s; red[wave + 4] = s2; }
        __syncthreads();
        if (threadIdx.x == 0) {
            float ts = red[0] + red[1] + red[2] + red[3];
            float t2 = red[4] + red[5] + red[6] + red[7];
            float m = ts * (1.f / 16384.f);
            float v = t2 * (1.f / 16384.f) - m * m;
            mean[bc] = m;
            rstd[bc] = rsqrtf(v + EPS_);
        }
    } else {
        // prep
        float wb = 1.f / (1.f + __expf(-alpha_beta[0]));
        float wg = 1.f / (1.f + __expf(-alpha_gamma[0]));
        int gid = (bid - 3072) * 256 + threadIdx.x;
        if (gid < 256) bias_s[gid] = wg * b_sgamma[gid] + (1.f - wg) * b_gamma[gid];
        else if (gid < 512) bias_o[gid - 256] = wb * b_sbeta[gid - 256] + (1.f - wb) * b_beta[gid - 256];
        if (gid < 8192) zpage[gid] = 0.f;

        const int total = 9 * 512 * 640;
        for (int idx = gid; idx < total; idx += 2048 * 256) {
            int tap = idx / (512 * 640);
            int r = idx - tap * (512 * 640);
            int co = r / 640, ci = r - co * 640;
            int kh = tap / 3, kw = tap - kh * 3;
            float v;
            if (co < 256) {
                if (ci < 128) v = (1.f - wg) * w_gamma[((co * 128 + ci) * 3 + kh) * 3 + kw];
                else          v = wg * w_sgamma[((co * 512 + (ci - 128)) * 3 + kh) * 3 + kw];
            } else {
                int c2 = co - 256;
                if (ci < 128) v = (1.f - wb) * w_beta[((c2 * 128 + ci) * 3 + kh) * 3 + kw];
                else          v = wb * w_sbeta[((c2 * 512 + (ci - 128)) * 3 + kh) * 3 + kw];
            }
            Wt[idx] = f2b(v);
        }
    }
}

// ---------------- kernel 3: main implicit-GEMM conv + fused epilogue (R6/R12 body) -------
// 512 threads (8 waves, 4wm x 2wn). M = 256 px (2 rows), N = 256 (128 scale + 128 offset).
// BK=32. LDS: A dbuf 2x32KB + B triple-buf 3x16KB = 112KB (reg-capped at 2 waves/SIMD:
// 128 arch + 128 acc = 256/wave).
// Deep pipeline: B(g) staged at g-2; raw s_barrier + counted vmcnt; A' staged at tap 7.
// LDS slot swizzle: phys_slot = data_slot ^ ((row>>1)&3) -> conflict-free (R6-verified).
#define BK 32

__global__ void __launch_bounds__(512, 1) k_conv(
    const ushort_t* __restrict__ U, const ushort_t* __restrict__ Wt,
    const ushort_t* __restrict__ zp,
    const float* __restrict__ x, const float* __restrict__ mean, const float* __restrict__ rstd,
    const float* __restrict__ bias_s, const float* __restrict__ bias_o,
    float* __restrict__ out)
{
    // bijective XCD-chunk swizzle (nwg=1024, 128 per XCD)
    int orig = blockIdx.x;
    int wg = (orig & 7) * 128 + (orig >> 3);
    int mtile = wg >> 1;
    int cohalf = wg & 1;
    int b = mtile >> 6;
    int h0 = (mtile & 63) << 1;

    extern __shared__ ushort_t smem[];
    // smem + ab*16384        : sA[2]  (each 4 rows x 128 px x 32 ci = 32KB)
    // smem + 32768 + bi*8192 : sB[3]  (each 256 ch x 32 ci = 16KB)

    int t = threadIdx.x;
    int wv = t >> 6, ln = t & 63;
    int wm = wv >> 1, wn = wv & 1;

    const ushort_t* Ub = U + (size_t)b * (H_ * W_ * UC);

    f4v acc[4][8] = {};   // [mi][ni]; ni<4 scale, ni>=4 offset (same channels)

    auto stage_A = [&](int ci0, int ab) {      // 4 loads/thread -> 32KB
        ushort_t* sAb = smem + ab * 16384;
        #pragma unroll
        for (int i = 0; i < 4; ++i) {
            int issue = wv * 4 + i;            // 32 issues of 1KB
            int hh = h0 - 1 + (issue >> 3);    // wave-uniform row
            int w = issue * 16 + (ln >> 2);
            int sl = (ln & 3) ^ ((w >> 1) & 3);    // inverse-swizzled source slot
            const ushort_t* src = (hh >= 0 && hh < H_)
                ? Ub + ((size_t)hh * W_ + (w & 127)) * UC + ci0 + (sl << 3)
                : zp + (size_t)ln * 8;
            gl2lds16(src, sAb + (size_t)issue * 512);
        }
    };
    auto stage_B = [&](int tapX, int ci0X, int bi) {   // 2 loads/thread -> 16KB
        ushort_t* base = smem + 32768 + bi * 8192;
        #pragma unroll
        for (int j = 0; j < 2; ++j) {
            int issue = wv * 2 + j;            // 16 issues of 1KB
            int c = issue * 16 + (ln >> 2);    // LDS row (0..255)
            int sl = (ln & 3) ^ ((c >> 1) & 3);
            int gq = (c >> 6) & 1;
            int cbase = ((c >> 7) << 6) + (c & 63);
            int co = gq * 256 + cohalf * 128 + cbase;
            const ushort_t* src = Wt + ((size_t)tapX * 512 + co) * UC + ci0X + (sl << 3);
            gl2lds16(src, base + (size_t)issue * 512);
        }
    };

    // ---- prologue: A(ch0), B(g=0), B(g=1) ----
    stage_A(0, 0);
    stage_B(0, 0, 0);
    stage_B(1, 0, 1);

    for (int ch = 0; ch < 20; ++ch) {
        int ci0 = ch * BK;
        ushort_t* sAb = smem + (ch & 1) * 16384;
        bool lastch = (ch == 19);
        #pragma unroll
        for (int tap = 0; tap < 9; ++tap) {
            const int dhp1 = tap / 3;            // compile-time after unroll
            const int dw = tap - dhp1 * 3 - 1;
            const int bi = tap % 3;              // 9 % 3 == 0 -> per-tap constant
            const int bi2 = (tap + 2) % 3;

            // counted waits: own B (and A at chunk entry) landed; newer loads in flight
            if (tap == 8) {
                if (lastch) { asm volatile("s_waitcnt vmcnt(0)" ::: "memory"); }
                else        { asm volatile("s_waitcnt vmcnt(6)" ::: "memory"); }
            } else          { asm volatile("s_waitcnt vmcnt(2)" ::: "memory"); }
            __builtin_amdgcn_s_barrier();

            // prefetch body g+2 (B), and next chunk's A at tap 7 (after B, order matters)
            if (tap < 7)        stage_B(tap + 2, ci0, bi2);
            else if (!lastch) {
                if (tap == 7) { stage_B(0, ci0 + BK, bi2); stage_A(ci0 + BK, (ch + 1) & 1); }
                else          stage_B(1, ci0 + BK, bi2);
            }

            // ---- compute: sA rows dhp1..dhp1+1 (dw shift), sB[bi] ----
            ushort_t* sBb = smem + 32768 + bi * 8192;
            int sd = ln >> 4;                 // 16B k-slot
            s8v af[4];
            #pragma unroll
            for (int mi = 0; mi < 4; ++mi) {
                int p = wm * 64 + mi * 16 + (ln & 15);
                int q = (p & 127) + dw;
                int qc = q < 0 ? 0 : (q > 127 ? 127 : q);
                int r = (p >> 7) + dhp1;
                s8v v = *(const s8v*)&sAb[(size_t)(((r * 128 + qc) << 2) + (sd ^ ((qc >> 1) & 3))) * 8];
                if (dw != 0 && (q < 0 || q > 127)) { s8v z = {}; v = z; }
                af[mi] = v;
            }
            s8v bf[8];
            #pragma unroll
            for (int ni = 0; ni < 8; ++ni) {
                int c = wn * 128 + (ni >> 2) * 64 + (ni & 3) * 16 + (ln & 15);
                bf[ni] = *(const s8v*)&sBb[(size_t)((c << 2) + (sd ^ ((c >> 1) & 3))) * 8];
            }
            __builtin_amdgcn_s_setprio(1);
            #pragma unroll
            for (int mi = 0; mi < 4; ++mi)
                #pragma unroll
                for (int ni = 0; ni < 8; ++ni)
                    acc[mi][ni] = __builtin_amdgcn_mfma_f32_16x16x32_bf16(
                        af[mi], bf[ni], acc[mi][ni], 0, 0, 0);
            __builtin_amdgcn_s_setprio(0);
        }
    }

    // ---- fused epilogue: out = (x-mu)*rstd*(scale+bs+1) + (offset+bo) ----
    int bc_base = b * 256;
    #pragma unroll
    for (int ni = 0; ni < 4; ++ni) {
        int chn = cohalf * 128 + wn * 64 + ni * 16 + (ln & 15);
        float bs = bias_s[chn] + 1.f;
        float bo = bias_o[chn];
        float mu = mean[bc_base + chn];
        float rs = rstd[bc_base + chn];
        #pragma unroll
        for (int mi = 0; mi < 4; ++mi) {
            #pragma unroll
            for (int r = 0; r < 4; ++r) {
                int p = wm * 64 + mi * 16 + ((ln >> 4) << 2) + r;
                int hh = h0 + (p >> 7);
                int ww = p & 127;
                size_t xi = (((size_t)(bc_base + chn)) * H_ + hh) * W_ + ww;
                float xn = (x[xi] - mu) * rs;
                out[xi] = xn * (acc[mi][ni][r] + bs) + (acc[mi][ni + 4][r] + bo);
            }
        }
    }
}

// ---------------- launcher ----------------
extern "C" void kernel_launch(void* const* d_in, const int* in_sizes, int n_in,
                              void* d_out, int out_size, void* d_ws, size_t ws_size,
                              hipStream_t stream)
{
    const float* x        = (const float*)d_in[0];
    const float* segmap   = (const float*)d_in[1];
    const float* style    = (const float*)d_in[2];
    const float* w_shared = (const float*)d_in[3];
    const float* b_shared = (const float*)d_in[4];
    const float* w_gamma  = (const float*)d_in[5];
    const float* b_gamma  = (const float*)d_in[6];
    const float* w_beta   = (const float*)d_in[7];
    const float* b_beta   = (const float*)d_in[8];
    const float* w_sgamma = (const float*)d_in[9];
    const float* b_sgamma = (const float*)d_in[10];
    const float* w_sbeta  = (const float*)d_in[11];
    const float* b_sbeta  = (const float*)d_in[12];
    const float* alpha_beta  = (const float*)d_in[13];
    const float* alpha_gamma = (const float*)d_in[14];
    float* out = (float*)d_out;

    char* ws = (char*)d_ws;
    float*    ws_mean  = (float*)(ws + 0);            // 2048 f32
    float*    ws_rstd  = (float*)(ws + 8192);         // 2048 f32
    float*    ws_bs    = (float*)(ws + 16384);        // 256 f32
    float*    ws_bo    = (float*)(ws + 18432);        // 256 f32
    ushort_t* ws_Wt    = (ushort_t*)(ws + 20480);     // 9*512*640 bf16 = 5.9 MB
    ushort_t* ws_zp    = (ushort_t*)(ws + 6 * 1024 * 1024 - 65536);  // 32KB zero page
    ushort_t* ws_U     = (ushort_t*)(ws + 6 * 1024 * 1024);  // 8*128*128*640 bf16 = 167.8 MB

    (void)hipFuncSetAttribute((const void*)k_conv,
                              hipFuncAttributeMaxDynamicSharedMemorySize, 114688);

    k_aux<<<dim3(5120), dim3(256), 0, stream>>>(x, segmap, style, w_shared, b_shared,
                                                w_gamma, w_beta, w_sgamma, w_sbeta,
                                                b_gamma, b_beta, b_sgamma, b_sbeta,
                                                alpha_beta, alpha_gamma,
                                                ws_U, ws_Wt, ws_mean, ws_rstd,
                                                ws_bs, ws_bo, (float*)ws_zp);
    k_conv<<<dim3(1024), dim3(512), 114688, stream>>>(ws_U, ws_Wt, ws_zp, x, ws_mean, ws_rstd,
                                                      ws_bs, ws_bo, out);
}